// Round 8
// baseline (352.208 us; speedup 1.0000x reference)
//
#include <hip/hip_runtime.h>
#include <hip/hip_bf16.h>
#include <stdint.h>

#define NNODES 50000
#define NEDGES 100000

typedef __attribute__((ext_vector_type(8))) short short8;
typedef __attribute__((ext_vector_type(4))) float f32x4;

__device__ __forceinline__ unsigned short f2bf(float f) {
    union { unsigned int i; float f; } v; v.f = f;
    unsigned int r = v.i + 0x7FFFu + ((v.i >> 16) & 1u);  // RNE
    return (unsigned short)(r >> 16);
}
__device__ __forceinline__ float bf2f(unsigned short u) {
    union { unsigned int i; float f; } v; v.i = ((unsigned int)u) << 16; return v.f;
}
__device__ __forceinline__ void gload16(const void* g, void* lds) {
    __builtin_amdgcn_global_load_lds(
        (const __attribute__((address_space(1))) unsigned int*)g,
        (__attribute__((address_space(3))) unsigned int*)lds, 16, 0, 0);
}

// ---------------------------------------------------------------------------
// Pack W2 fp32[1024][1024] -> bf16 B-frag panels (coalesced reads):
// w2p[(((nb*32+ks)*4+kg)*128+n)*8+j] = W2[k][col], k=ks*32+kg*8+j, col=nb*128+n
// ---------------------------------------------------------------------------
__global__ __launch_bounds__(256) void k_pack(const float* __restrict__ W2,
                                              unsigned short* __restrict__ w2p) {
    const int idx = blockIdx.x * 256 + threadIdx.x;   // 1M elements
    const int k = idx >> 10, col = idx & 1023;
    const float v = W2[idx];
    const int nb = col >> 7, n = col & 127;
    const int ks = k >> 5, kg = (k >> 3) & 3, j = k & 7;
    w2p[((((size_t)nb * 32 + ks) * 4 + kg) * 128 + n) * 8 + j] = f2bf(v);
}

// ---------------------------------------------------------------------------
// Pack W1 fp32[32][1024] -> bf16 A-frag panels of W1^T (M = h1-col, K = ef-feat)
// ---------------------------------------------------------------------------
__global__ __launch_bounds__(256) void k_packw1(const float* __restrict__ W1,
                                                unsigned short* __restrict__ w1pT) {
    const int idx = blockIdx.x * 256 + threadIdx.x;   // 32768 elements
    const int i = idx >> 10, col = idx & 1023;
    const float v = W1[idx];
    const int ks = col >> 5, c = col & 31;
    const int kt = c >> 4, lr = c & 15;
    const int lq = i >> 3, ii = i & 7;
    w1pT[((((size_t)ks * 2 + kt) * 4 + lq) * 16 + lr) * 8 + ii] = f2bf(v);
}

// ---------------------------------------------------------------------------
// Fused edge kernel: 128 edges/block, waves = 2x2 (wm: edge-half, wc: col-half),
// 4 passes of 256 cols. h1 via MFMA, sH DOUBLE-BUFFERED by ks-parity ->
// ONE barrier per K-step (R7 had two; the (a)->(b) segment was 4 ds_writes +
// a full vmcnt/lgkm drain = pure serialization).
// Per-ks order: h1-MFMA -> STORE_H1(sH[ph]) -> barrier (drains prev stage) ->
// STAGE next slab (flies across MFMA phase) -> ds_read -> 32 MFMA.
// ---------------------------------------------------------------------------
__global__ __launch_bounds__(256, 2) void k_gemm(
    const unsigned short* __restrict__ w2p, const unsigned short* __restrict__ w1pT,
    const float* __restrict__ ef, const float* __restrict__ nf,
    const float* __restrict__ b1, const float* __restrict__ b2,
    const int* __restrict__ src, const int* __restrict__ dst,
    float* __restrict__ agg, float* __restrict__ deg)
{
    __shared__ __align__(16) unsigned short sB[2][8192];   // W2 2-panel dbuf (32KB); pre-loop: sB[0]=ef frags; post: sRed
    __shared__ __align__(16) unsigned short sH[2][4096];   // h1 A-frags, ks-parity dbuf (16KB)
    __shared__ __align__(16) unsigned short sXb[4096];     // x A-frags (8KB)
    __shared__ int sD[128];

    const int t    = threadIdx.x;
    const int lane = t & 63;
    const int w    = t >> 6;
    const int wm   = w >> 1, wc = w & 1;    // edge-half, col-half
    const int lq   = lane >> 4, lr = lane & 15;
    const int e0   = blockIdx.x * 128;

    unsigned short* sE = sB[0];   // ef^T B-frag panel, pre-loop only

    // ---- phase 0: ef -> sE (B-frags), x=nf[src] -> sXb (A-frags), sD ----
    {
        const int e = t >> 1, fo = (t & 1) * 16;
        const int eg = e0 + e;
        const bool valid = eg < NEDGES;
        const int iq = fo >> 3;
        unsigned short hh[16];
        uint4 pa, pb;

        #pragma unroll
        for (int q = 0; q < 4; ++q) {
            float4 v = valid ? *(const float4*)(ef + (size_t)eg * 32 + fo + q * 4)
                             : float4{0.f, 0.f, 0.f, 0.f};
            hh[q*4+0] = f2bf(v.x); hh[q*4+1] = f2bf(v.y);
            hh[q*4+2] = f2bf(v.z); hh[q*4+3] = f2bf(v.w);
        }
        pa.x = hh[0] | ((unsigned)hh[1] << 16);  pa.y = hh[2]  | ((unsigned)hh[3] << 16);
        pa.z = hh[4] | ((unsigned)hh[5] << 16);  pa.w = hh[6]  | ((unsigned)hh[7] << 16);
        pb.x = hh[8] | ((unsigned)hh[9] << 16);  pb.y = hh[10] | ((unsigned)hh[11] << 16);
        pb.z = hh[12]| ((unsigned)hh[13] << 16); pb.w = hh[14] | ((unsigned)hh[15] << 16);
        *(uint4*)(sE + ((iq    ) * 128 + e) * 8) = pa;
        *(uint4*)(sE + ((iq + 1) * 128 + e) * 8) = pb;

        const int s = valid ? src[eg] : 0;
        #pragma unroll
        for (int q = 0; q < 4; ++q) {
            float4 xv = valid ? *(const float4*)(nf + (size_t)s * 32 + fo + q * 4)
                              : float4{0.f, 0.f, 0.f, 0.f};
            hh[q*4+0] = f2bf(xv.x); hh[q*4+1] = f2bf(xv.y);
            hh[q*4+2] = f2bf(xv.z); hh[q*4+3] = f2bf(xv.w);
        }
        pa.x = hh[0] | ((unsigned)hh[1] << 16);  pa.y = hh[2]  | ((unsigned)hh[3] << 16);
        pa.z = hh[4] | ((unsigned)hh[5] << 16);  pa.w = hh[6]  | ((unsigned)hh[7] << 16);
        pb.x = hh[8] | ((unsigned)hh[9] << 16);  pb.y = hh[10] | ((unsigned)hh[11] << 16);
        pb.z = hh[12]| ((unsigned)hh[13] << 16); pb.w = hh[14] | ((unsigned)hh[15] << 16);
        *(uint4*)(sXb + ((iq    ) * 128 + e) * 8) = pa;
        *(uint4*)(sXb + ((iq + 1) * 128 + e) * 8) = pb;
    }
    if (t < 128) {
        const int eg = e0 + t;
        const int dv = (eg < NEDGES) ? dst[eg] : -1;
        sD[t] = dv;
        if (dv >= 0) atomicAdd(&deg[dv], 1.0f);
    }
    __syncthreads();

    // hoisted ef^T B-frags for this wave's 32 h1-production edges (base w*32)
    const short8 bfe0 = *(const short8*)(sE + (lq * 128 + w * 32 + lr) * 8);
    const short8 bfe1 = *(const short8*)(sE + (lq * 128 + w * 32 + 16 + lr) * 8);

    // ---- pm init: pm[e,o] = sum_i x[e,i]*b2[i*32+o], by wc==0 waves ONLY ----
    f32x4 pm[8];   // [mt*2 + o-half]; layout col=o=lr(+16*half), row=e=wm*64+mt*16+lq*4+r
    #pragma unroll
    for (int i = 0; i < 8; ++i) pm[i] = f32x4{0.f, 0.f, 0.f, 0.f};
    if (wc == 0) {
        short8 bb0, bb1;
        #pragma unroll
        for (int j = 0; j < 8; ++j) {
            bb0[j] = (short)f2bf(b2[(lq * 8 + j) * 32 + lr]);
            bb1[j] = (short)f2bf(b2[(lq * 8 + j) * 32 + 16 + lr]);
        }
        #pragma unroll
        for (int mt = 0; mt < 4; ++mt) {
            const short8 xf = *(const short8*)(sXb + (lq * 128 + wm * 64 + mt * 16 + lr) * 8);
            pm[mt * 2]     = __builtin_amdgcn_mfma_f32_16x16x32_bf16(xf, bb0, pm[mt * 2],     0, 0, 0);
            pm[mt * 2 + 1] = __builtin_amdgcn_mfma_f32_16x16x32_bf16(xf, bb1, pm[mt * 2 + 1], 0, 0, 0);
        }
    }
    __syncthreads();   // all waves done reading sE before staging overwrites sB[0]

    #define STAGE2(dstb, nblk_, ks_) do {                                          \
        const unsigned short* _g0 = w2p + ((size_t)((nblk_) * 32 + (ks_)) * 4096); \
        const unsigned short* _g1 = _g0 + (size_t)32 * 4096;                       \
        gload16(_g0 + (size_t)t * 8,         (dstb) + w * 512);                    \
        gload16(_g0 + (size_t)(t + 256) * 8, (dstb) + 2048 + w * 512);             \
        gload16(_g1 + (size_t)t * 8,         (dstb) + 4096 + w * 512);             \
        gload16(_g1 + (size_t)(t + 256) * 8, (dstb) + 6144 + w * 512);             \
    } while (0)

    STAGE2(sB[0], 0, 0);

    short8 w1c0 = *(const short8*)(w1pT + ((0 * 4 + lq) * 16 + lr) * 8);
    short8 w1c1 = *(const short8*)(w1pT + ((1 * 4 + lq) * 16 + lr) * 8);
    float4 b1c0 = *(const float4*)(b1 + lq * 4);
    float4 b1c1 = *(const float4*)(b1 + 16 + lq * 4);

    int buf = 0;
    for (int nbp = 0; nbp < 4; ++nbp) {
        const int nblk0 = nbp * 2;
        f32x4 acc[4][8];
        #pragma unroll
        for (int mt = 0; mt < 4; ++mt)
            #pragma unroll
            for (int nt = 0; nt < 8; ++nt) acc[mt][nt] = f32x4{0.f, 0.f, 0.f, 0.f};

        for (int ks = 0; ks < 32; ++ks) {
            unsigned short* sHp = sH[ks & 1];

            // ---- h1 compute (register-only) ----
            f32x4 h00 = {b1c0.x, b1c0.y, b1c0.z, b1c0.w};
            f32x4 h01 = h00;
            f32x4 h10 = {b1c1.x, b1c1.y, b1c1.z, b1c1.w};
            f32x4 h11 = h10;
            h00 = __builtin_amdgcn_mfma_f32_16x16x32_bf16(w1c0, bfe0, h00, 0, 0, 0);
            h01 = __builtin_amdgcn_mfma_f32_16x16x32_bf16(w1c0, bfe1, h01, 0, 0, 0);
            h10 = __builtin_amdgcn_mfma_f32_16x16x32_bf16(w1c1, bfe0, h10, 0, 0, 0);
            h11 = __builtin_amdgcn_mfma_f32_16x16x32_bf16(w1c1, bfe1, h11, 0, 0, 0);

            #define STORE_H1(hv, kt, et) do {                                           \
                float r0 = fmaxf((hv)[0], 0.f), r1 = fmaxf((hv)[1], 0.f);               \
                float r2 = fmaxf((hv)[2], 0.f), r3 = fmaxf((hv)[3], 0.f);               \
                unsigned p0, p1;                                                         \
                asm("v_cvt_pk_bf16_f32 %0, %1, %2" : "=v"(p0) : "v"(r0), "v"(r1));       \
                asm("v_cvt_pk_bf16_f32 %0, %1, %2" : "=v"(p1) : "v"(r2), "v"(r3));       \
                uint2 pk; pk.x = p0; pk.y = p1;                                          \
                *(uint2*)(sHp + ((((kt) * 2 + (lq >> 1)) * 128 + w * 32 + (et) * 16 + lr)\
                    * 8 + (lq & 1) * 4)) = pk;                                           \
            } while (0)
            STORE_H1(h00, 0, 0); STORE_H1(h01, 0, 1);
            STORE_H1(h10, 1, 0); STORE_H1(h11, 1, 1);
            #undef STORE_H1

            __syncthreads();   // ONE barrier: sH[ph] complete; prev stage drained

            // stage next W2 slab (flies across the MFMA phase, drains next barrier)
            {
                int nks = ks + 1, nnb = nblk0;
                if (nks == 32) { nks = 0; nnb = nblk0 + 2; }
                if (!(nbp == 3 && ks == 31)) STAGE2(sB[buf ^ 1], nnb, nks);
            }
            const int nks2 = (ks == 31) ? 0 : ks + 1;
            short8 w1n0 = *(const short8*)(w1pT + ((((size_t)nks2 * 2 + 0) * 4 + lq) * 16 + lr) * 8);
            short8 w1n1 = *(const short8*)(w1pT + ((((size_t)nks2 * 2 + 1) * 4 + lq) * 16 + lr) * 8);
            float4 b1n0 = *(const float4*)(b1 + nks2 * 32 + lq * 4);
            float4 b1n1 = *(const float4*)(b1 + nks2 * 32 + 16 + lq * 4);

            // ---- main MFMA: A = shared h1 (wm edge-half), B = wc col-panel ----
            const short8 af0 = *(const short8*)(sHp + (lq * 128 + wm * 64 +  0 + lr) * 8);
            const short8 af1 = *(const short8*)(sHp + (lq * 128 + wm * 64 + 16 + lr) * 8);
            const short8 af2 = *(const short8*)(sHp + (lq * 128 + wm * 64 + 32 + lr) * 8);
            const short8 af3 = *(const short8*)(sHp + (lq * 128 + wm * 64 + 48 + lr) * 8);
            const unsigned short* pb = sB[buf] + wc * 4096;
            #pragma unroll
            for (int nt = 0; nt < 8; ++nt) {
                const short8 bf = *(const short8*)(pb + (lq * 128 + nt * 16 + lr) * 8);
                acc[0][nt] = __builtin_amdgcn_mfma_f32_16x16x32_bf16(af0, bf, acc[0][nt], 0, 0, 0);
                acc[1][nt] = __builtin_amdgcn_mfma_f32_16x16x32_bf16(af1, bf, acc[1][nt], 0, 0, 0);
                acc[2][nt] = __builtin_amdgcn_mfma_f32_16x16x32_bf16(af2, bf, acc[2][nt], 0, 0, 0);
                acc[3][nt] = __builtin_amdgcn_mfma_f32_16x16x32_bf16(af3, bf, acc[3][nt], 0, 0, 0);
            }
            buf ^= 1;
            w1c0 = w1n0; w1c1 = w1n1; b1c0 = b1n0; b1c1 = b1n1;
        }

        // ---- fold this wave's panel into pm: pm[e,o] += x[e,i] * w[e,32i+o] ----
        {
            const int nblk = nblk0 + wc;
            #pragma unroll
            for (int ii = 0; ii < 4; ++ii) {
                const int i  = nblk * 4 + ii;
                const int iq = i >> 3, io = i & 7;
                #pragma unroll
                for (int mt = 0; mt < 4; ++mt)
                    #pragma unroll
                    for (int r = 0; r < 4; ++r) {
                        const int e = wm * 64 + mt * 16 + lq * 4 + r;
                        const float x = bf2f(sXb[iq * 1024 + e * 8 + io]);
                        pm[mt*2+0][r] = fmaf(x, acc[mt][ii*2+0][r], pm[mt*2+0][r]);
                        pm[mt*2+1][r] = fmaf(x, acc[mt][ii*2+1][r], pm[mt*2+1][r]);
                    }
            }
        }
    }
    #undef STAGE2

    // ---- cross-wc reduce in dead sB ----
    __syncthreads();
    float* sRed = (float*)sB;   // 128 x 36 fp32 = 18.4KB <= 32KB
    if (wc == 0) {
        #pragma unroll
        for (int mt = 0; mt < 4; ++mt)
            #pragma unroll
            for (int r = 0; r < 4; ++r) {
                const int e = wm * 64 + mt * 16 + lq * 4 + r;
                sRed[e * 36 + lr]      = pm[mt*2][r];
                sRed[e * 36 + 16 + lr] = pm[mt*2+1][r];
            }
    }
    __syncthreads();
    if (wc == 1) {
        #pragma unroll
        for (int mt = 0; mt < 4; ++mt)
            #pragma unroll
            for (int r = 0; r < 4; ++r) {
                const int e = wm * 64 + mt * 16 + lq * 4 + r;
                sRed[e * 36 + lr]      += pm[mt*2][r];
                sRed[e * 36 + 16 + lr] += pm[mt*2+1][r];
            }
    }
    __syncthreads();

    // ---- scatter, R4-shaped: lanes = 4 edges (lq) x 16 consecutive cols (lr)
    // so the TCC merges each instruction's dwords into line ops.
    #pragma unroll
    for (int mt = 0; mt < 2; ++mt)
        #pragma unroll
        for (int r = 0; r < 4; ++r) {
            const int e = w * 32 + mt * 16 + lq * 4 + r;
            const int d = sD[e];
            if (d >= 0) {
                atomicAdd(agg + (size_t)d * 32 + lr,      sRed[e * 36 + lr]);
                atomicAdd(agg + (size_t)d * 32 + 16 + lr, sRed[e * 36 + 16 + lr]);
            }
        }
}

// h[n,o] = relu(agg/max(deg,1) + bias), in place over agg
__global__ __launch_bounds__(256) void k_node(
    float* __restrict__ agg, const float* __restrict__ deg,
    const float* __restrict__ cbias)
{
    const int idx = blockIdx.x * 256 + threadIdx.x;
    if (idx >= NNODES * 32) return;
    const int n = idx >> 5, o = idx & 31;
    const float d = fmaxf(deg[n], 1.0f);
    agg[idx] = fmaxf(agg[idx] / d + cbias[o], 0.0f);
}

__global__ __launch_bounds__(256) void k_cls(
    const float* __restrict__ h, const float* __restrict__ ef,
    const int* __restrict__ src, const int* __restrict__ dst,
    const int* __restrict__ eidx,
    const float* __restrict__ Wc1, const float* __restrict__ bc1,
    const float* __restrict__ Wc2, const float* __restrict__ bc2,
    float* __restrict__ out)
{
    __shared__ float s_w1[96 * 32];
    __shared__ float s_w2[96];
    __shared__ float s_b1[32];
    __shared__ float s_in[8][96];

    const int t = threadIdx.x;
    #pragma unroll
    for (int q = 0; q < 3; ++q)
        *(float4*)&s_w1[t * 12 + q * 4] = *(const float4*)&Wc1[t * 12 + q * 4];
    if (t < 96) s_w2[t] = Wc2[t];
    if (t >= 96 && t < 128) s_b1[t - 96] = bc1[t - 96];

    const int ee = t >> 5, l = t & 31;
    const int e  = blockIdx.x * 8 + ee;
    const int ei = eidx[e];
    const int s = src[ei], d = dst[ei];
    s_in[ee][l]      = h[(size_t)s * 32 + l];
    s_in[ee][32 + l] = h[(size_t)d * 32 + l];
    s_in[ee][64 + l] = ef[(size_t)ei * 32 + l];
    __syncthreads();

    float acc = s_b1[l];
    #pragma unroll
    for (int c = 0; c < 96; ++c) acc = fmaf(s_in[ee][c], s_w1[c * 32 + l], acc);
    acc = fmaxf(acc, 0.f);

    float p0 = acc * s_w2[l * 3 + 0];
    float p1 = acc * s_w2[l * 3 + 1];
    float p2 = acc * s_w2[l * 3 + 2];
    #pragma unroll
    for (int m = 1; m <= 16; m <<= 1) {
        p0 += __shfl_xor(p0, m);
        p1 += __shfl_xor(p1, m);
        p2 += __shfl_xor(p2, m);
    }
    if (l == 0) {
        out[(size_t)e * 3 + 0] = p0 + bc2[0];
        out[(size_t)e * 3 + 1] = p1 + bc2[1];
        out[(size_t)e * 3 + 2] = p2 + bc2[2];
    }
}

extern "C" void kernel_launch(void* const* d_in, const int* in_sizes, int n_in,
                              void* d_out, int out_size, void* d_ws, size_t ws_size,
                              hipStream_t stream) {
    const float* nf   = (const float*)d_in[0];
    const float* ef   = (const float*)d_in[1];
    const int*   src  = (const int*)d_in[2];
    const int*   dst  = (const int*)d_in[3];
    const int*   eidx = (const int*)d_in[4];
    const float* W1   = (const float*)d_in[5];
    const float* b1   = (const float*)d_in[6];
    const float* W2   = (const float*)d_in[7];
    const float* b2   = (const float*)d_in[8];
    const float* cb   = (const float*)d_in[9];
    const float* Wc1  = (const float*)d_in[10];
    const float* bc1  = (const float*)d_in[11];
    const float* Wc2  = (const float*)d_in[12];
    const float* bc2  = (const float*)d_in[13];
    float* out = (float*)d_out;

    float* agg = (float*)d_ws;                               // 1,600,000 f32
    float* deg = agg + (size_t)NNODES * 32;                  // 50,000 f32
    unsigned short* w2p  = (unsigned short*)(deg + NNODES);  // 1,048,576 bf16
    unsigned short* w1pT = w2p + 1048576;                    // 32,768 bf16

    hipMemsetAsync(d_ws, 0, ((size_t)NNODES * 32 + NNODES) * 4, stream);
    k_pack<<<4096, 256, 0, stream>>>(W2, w2p);
    k_packw1<<<128, 256, 0, stream>>>(W1, w1pT);

    k_gemm<<<(NEDGES + 127) / 128, 256, 0, stream>>>(
        w2p, w1pT, ef, nf, b1, b2, src, dst, agg, deg);

    k_node<<<(NNODES * 32 + 255) / 256, 256, 0, stream>>>(agg, deg, cb);
    k_cls<<<NEDGES / 8, 256, 0, stream>>>(agg, ef, src, dst, eidx, Wc1, bc1, Wc2, bc2, out);
}

// Round 9
// 333.605 us; speedup vs baseline: 1.0558x; 1.0558x over previous
//
#include <hip/hip_runtime.h>
#include <hip/hip_bf16.h>
#include <stdint.h>

#define NNODES 50000
#define NEDGES 100000

typedef __attribute__((ext_vector_type(8))) short short8;
typedef __attribute__((ext_vector_type(4))) float f32x4;

__device__ __forceinline__ unsigned short f2bf(float f) {
    union { unsigned int i; float f; } v; v.f = f;
    unsigned int r = v.i + 0x7FFFu + ((v.i >> 16) & 1u);  // RNE
    return (unsigned short)(r >> 16);
}
__device__ __forceinline__ float bf2f(unsigned short u) {
    union { unsigned int i; float f; } v; v.i = ((unsigned int)u) << 16; return v.f;
}
__device__ __forceinline__ void gload16(const void* g, void* lds) {
    __builtin_amdgcn_global_load_lds(
        (const __attribute__((address_space(1))) unsigned int*)g,
        (__attribute__((address_space(3))) unsigned int*)lds, 16, 0, 0);
}

// ---------------------------------------------------------------------------
// Pack W2 fp32[1024][1024] -> bf16 B-frag panels (coalesced reads):
// w2p[(((nb*32+ks)*4+kg)*128+n)*8+j] = W2[k][col], k=ks*32+kg*8+j, col=nb*128+n
// ---------------------------------------------------------------------------
__global__ __launch_bounds__(256) void k_pack(const float* __restrict__ W2,
                                              unsigned short* __restrict__ w2p) {
    const int idx = blockIdx.x * 256 + threadIdx.x;   // 1M elements
    const int k = idx >> 10, col = idx & 1023;
    const float v = W2[idx];
    const int nb = col >> 7, n = col & 127;
    const int ks = k >> 5, kg = (k >> 3) & 3, j = k & 7;
    w2p[((((size_t)nb * 32 + ks) * 4 + kg) * 128 + n) * 8 + j] = f2bf(v);
}

// ---------------------------------------------------------------------------
// Pack W1 fp32[32][1024] -> bf16 A-frag panels of W1^T (M = h1-col, K = ef-feat)
// ---------------------------------------------------------------------------
__global__ __launch_bounds__(256) void k_packw1(const float* __restrict__ W1,
                                                unsigned short* __restrict__ w1pT) {
    const int idx = blockIdx.x * 256 + threadIdx.x;   // 32768 elements
    const int i = idx >> 10, col = idx & 1023;
    const float v = W1[idx];
    const int ks = col >> 5, c = col & 31;
    const int kt = c >> 4, lr = c & 15;
    const int lq = i >> 3, ii = i & 7;
    w1pT[((((size_t)ks * 2 + kt) * 4 + lq) * 16 + lr) * 8 + ii] = f2bf(v);
}

// ---------------------------------------------------------------------------
// Fused edge kernel. Grid = (edge-tiles, 4): blockIdx.y = one 256-col pass
// (nbp loop hoisted to the grid to cut the 24% tail-quantization loss:
// 782 blocks on 512 slots -> 3128 shorter blocks, 76% -> 87% packing).
// Waves 2x2 (wm: edge-half, wc: col-half). h1 via MFMA, sH dbuf by ks-parity,
// one barrier per K-step. pm b2-init and deg on y==0 only; partial msg per
// y-block atomically accumulated into agg (linear, order-free).
// ---------------------------------------------------------------------------
__global__ __launch_bounds__(256, 2) void k_gemm(
    const unsigned short* __restrict__ w2p, const unsigned short* __restrict__ w1pT,
    const float* __restrict__ ef, const float* __restrict__ nf,
    const float* __restrict__ b1, const float* __restrict__ b2,
    const int* __restrict__ src, const int* __restrict__ dst,
    float* __restrict__ agg, float* __restrict__ deg)
{
    __shared__ __align__(16) unsigned short sB[2][8192];   // W2 2-panel dbuf (32KB); pre-loop: sB[0]=ef frags; post: sRed
    __shared__ __align__(16) unsigned short sH[2][4096];   // h1 A-frags, ks-parity dbuf (16KB)
    __shared__ __align__(16) unsigned short sXb[4096];     // x A-frags (8KB)
    __shared__ int sD[128];

    const int t    = threadIdx.x;
    const int lane = t & 63;
    const int w    = t >> 6;
    const int wm   = w >> 1, wc = w & 1;    // edge-half, col-half
    const int lq   = lane >> 4, lr = lane & 15;
    const int e0   = blockIdx.x * 128;
    const int yb   = blockIdx.y;            // which 256-col pass
    const int nblk0 = yb * 2;

    unsigned short* sE = sB[0];   // ef^T B-frag panel, pre-loop only

    // ---- phase 0: ef -> sE (B-frags), x=nf[src] -> sXb (A-frags), sD ----
    {
        const int e = t >> 1, fo = (t & 1) * 16;
        const int eg = e0 + e;
        const bool valid = eg < NEDGES;
        const int iq = fo >> 3;
        unsigned short hh[16];
        uint4 pa, pb;

        #pragma unroll
        for (int q = 0; q < 4; ++q) {
            float4 v = valid ? *(const float4*)(ef + (size_t)eg * 32 + fo + q * 4)
                             : float4{0.f, 0.f, 0.f, 0.f};
            hh[q*4+0] = f2bf(v.x); hh[q*4+1] = f2bf(v.y);
            hh[q*4+2] = f2bf(v.z); hh[q*4+3] = f2bf(v.w);
        }
        pa.x = hh[0] | ((unsigned)hh[1] << 16);  pa.y = hh[2]  | ((unsigned)hh[3] << 16);
        pa.z = hh[4] | ((unsigned)hh[5] << 16);  pa.w = hh[6]  | ((unsigned)hh[7] << 16);
        pb.x = hh[8] | ((unsigned)hh[9] << 16);  pb.y = hh[10] | ((unsigned)hh[11] << 16);
        pb.z = hh[12]| ((unsigned)hh[13] << 16); pb.w = hh[14] | ((unsigned)hh[15] << 16);
        *(uint4*)(sE + ((iq    ) * 128 + e) * 8) = pa;
        *(uint4*)(sE + ((iq + 1) * 128 + e) * 8) = pb;

        const int s = valid ? src[eg] : 0;
        #pragma unroll
        for (int q = 0; q < 4; ++q) {
            float4 xv = valid ? *(const float4*)(nf + (size_t)s * 32 + fo + q * 4)
                              : float4{0.f, 0.f, 0.f, 0.f};
            hh[q*4+0] = f2bf(xv.x); hh[q*4+1] = f2bf(xv.y);
            hh[q*4+2] = f2bf(xv.z); hh[q*4+3] = f2bf(xv.w);
        }
        pa.x = hh[0] | ((unsigned)hh[1] << 16);  pa.y = hh[2]  | ((unsigned)hh[3] << 16);
        pa.z = hh[4] | ((unsigned)hh[5] << 16);  pa.w = hh[6]  | ((unsigned)hh[7] << 16);
        pb.x = hh[8] | ((unsigned)hh[9] << 16);  pb.y = hh[10] | ((unsigned)hh[11] << 16);
        pb.z = hh[12]| ((unsigned)hh[13] << 16); pb.w = hh[14] | ((unsigned)hh[15] << 16);
        *(uint4*)(sXb + ((iq    ) * 128 + e) * 8) = pa;
        *(uint4*)(sXb + ((iq + 1) * 128 + e) * 8) = pb;
    }
    if (t < 128) {
        const int eg = e0 + t;
        const int dv = (eg < NEDGES) ? dst[eg] : -1;
        sD[t] = dv;
        if (yb == 0 && dv >= 0) atomicAdd(&deg[dv], 1.0f);
    }
    __syncthreads();

    // hoisted ef^T B-frags for this wave's 32 h1-production edges (base w*32)
    const short8 bfe0 = *(const short8*)(sE + (lq * 128 + w * 32 + lr) * 8);
    const short8 bfe1 = *(const short8*)(sE + (lq * 128 + w * 32 + 16 + lr) * 8);

    // ---- pm init: pm[e,o] = sum_i x[e,i]*b2[i*32+o] — y==0, wc==0 ONLY
    // (wc pairs and y-blocks all sum into the same (e,o); b2 must count once).
    f32x4 pm[8];   // [mt*2 + o-half]; layout col=o=lr(+16*half), row=e=wm*64+mt*16+lq*4+r
    #pragma unroll
    for (int i = 0; i < 8; ++i) pm[i] = f32x4{0.f, 0.f, 0.f, 0.f};
    if (yb == 0 && wc == 0) {
        short8 bb0, bb1;
        #pragma unroll
        for (int j = 0; j < 8; ++j) {
            bb0[j] = (short)f2bf(b2[(lq * 8 + j) * 32 + lr]);
            bb1[j] = (short)f2bf(b2[(lq * 8 + j) * 32 + 16 + lr]);
        }
        #pragma unroll
        for (int mt = 0; mt < 4; ++mt) {
            const short8 xf = *(const short8*)(sXb + (lq * 128 + wm * 64 + mt * 16 + lr) * 8);
            pm[mt * 2]     = __builtin_amdgcn_mfma_f32_16x16x32_bf16(xf, bb0, pm[mt * 2],     0, 0, 0);
            pm[mt * 2 + 1] = __builtin_amdgcn_mfma_f32_16x16x32_bf16(xf, bb1, pm[mt * 2 + 1], 0, 0, 0);
        }
    }
    __syncthreads();   // all waves done reading sE before staging overwrites sB[0]

    #define STAGE2(dstb, nblk_, ks_) do {                                          \
        const unsigned short* _g0 = w2p + ((size_t)((nblk_) * 32 + (ks_)) * 4096); \
        const unsigned short* _g1 = _g0 + (size_t)32 * 4096;                       \
        gload16(_g0 + (size_t)t * 8,         (dstb) + w * 512);                    \
        gload16(_g0 + (size_t)(t + 256) * 8, (dstb) + 2048 + w * 512);             \
        gload16(_g1 + (size_t)t * 8,         (dstb) + 4096 + w * 512);             \
        gload16(_g1 + (size_t)(t + 256) * 8, (dstb) + 6144 + w * 512);             \
    } while (0)

    STAGE2(sB[0], nblk0, 0);

    short8 w1c0 = *(const short8*)(w1pT + ((0 * 4 + lq) * 16 + lr) * 8);
    short8 w1c1 = *(const short8*)(w1pT + ((1 * 4 + lq) * 16 + lr) * 8);
    float4 b1c0 = *(const float4*)(b1 + lq * 4);
    float4 b1c1 = *(const float4*)(b1 + 16 + lq * 4);

    f32x4 acc[4][8];
    #pragma unroll
    for (int mt = 0; mt < 4; ++mt)
        #pragma unroll
        for (int nt = 0; nt < 8; ++nt) acc[mt][nt] = f32x4{0.f, 0.f, 0.f, 0.f};

    int buf = 0;
    for (int ks = 0; ks < 32; ++ks) {
        unsigned short* sHp = sH[ks & 1];

        // ---- h1 compute (register-only) ----
        f32x4 h00 = {b1c0.x, b1c0.y, b1c0.z, b1c0.w};
        f32x4 h01 = h00;
        f32x4 h10 = {b1c1.x, b1c1.y, b1c1.z, b1c1.w};
        f32x4 h11 = h10;
        h00 = __builtin_amdgcn_mfma_f32_16x16x32_bf16(w1c0, bfe0, h00, 0, 0, 0);
        h01 = __builtin_amdgcn_mfma_f32_16x16x32_bf16(w1c0, bfe1, h01, 0, 0, 0);
        h10 = __builtin_amdgcn_mfma_f32_16x16x32_bf16(w1c1, bfe0, h10, 0, 0, 0);
        h11 = __builtin_amdgcn_mfma_f32_16x16x32_bf16(w1c1, bfe1, h11, 0, 0, 0);

        #define STORE_H1(hv, kt, et) do {                                           \
            float r0 = fmaxf((hv)[0], 0.f), r1 = fmaxf((hv)[1], 0.f);               \
            float r2 = fmaxf((hv)[2], 0.f), r3 = fmaxf((hv)[3], 0.f);               \
            unsigned p0, p1;                                                         \
            asm("v_cvt_pk_bf16_f32 %0, %1, %2" : "=v"(p0) : "v"(r0), "v"(r1));       \
            asm("v_cvt_pk_bf16_f32 %0, %1, %2" : "=v"(p1) : "v"(r2), "v"(r3));       \
            uint2 pk; pk.x = p0; pk.y = p1;                                          \
            *(uint2*)(sHp + ((((kt) * 2 + (lq >> 1)) * 128 + w * 32 + (et) * 16 + lr)\
                * 8 + (lq & 1) * 4)) = pk;                                           \
        } while (0)
        STORE_H1(h00, 0, 0); STORE_H1(h01, 0, 1);
        STORE_H1(h10, 1, 0); STORE_H1(h11, 1, 1);
        #undef STORE_H1

        __syncthreads();   // sH[ph] complete; prev stage drained

        // stage next W2 slab (flies across the MFMA phase, drains next barrier)
        if (ks != 31) STAGE2(sB[buf ^ 1], nblk0, ks + 1);
        const int nks2 = (ks == 31) ? 0 : ks + 1;
        short8 w1n0 = *(const short8*)(w1pT + ((((size_t)nks2 * 2 + 0) * 4 + lq) * 16 + lr) * 8);
        short8 w1n1 = *(const short8*)(w1pT + ((((size_t)nks2 * 2 + 1) * 4 + lq) * 16 + lr) * 8);
        float4 b1n0 = *(const float4*)(b1 + nks2 * 32 + lq * 4);
        float4 b1n1 = *(const float4*)(b1 + nks2 * 32 + 16 + lq * 4);

        // ---- main MFMA: A = shared h1 (wm edge-half), B = wc col-panel ----
        const short8 af0 = *(const short8*)(sHp + (lq * 128 + wm * 64 +  0 + lr) * 8);
        const short8 af1 = *(const short8*)(sHp + (lq * 128 + wm * 64 + 16 + lr) * 8);
        const short8 af2 = *(const short8*)(sHp + (lq * 128 + wm * 64 + 32 + lr) * 8);
        const short8 af3 = *(const short8*)(sHp + (lq * 128 + wm * 64 + 48 + lr) * 8);
        const unsigned short* pb = sB[buf] + wc * 4096;
        __builtin_amdgcn_s_setprio(1);
        #pragma unroll
        for (int nt = 0; nt < 8; ++nt) {
            const short8 bf = *(const short8*)(pb + (lq * 128 + nt * 16 + lr) * 8);
            acc[0][nt] = __builtin_amdgcn_mfma_f32_16x16x32_bf16(af0, bf, acc[0][nt], 0, 0, 0);
            acc[1][nt] = __builtin_amdgcn_mfma_f32_16x16x32_bf16(af1, bf, acc[1][nt], 0, 0, 0);
            acc[2][nt] = __builtin_amdgcn_mfma_f32_16x16x32_bf16(af2, bf, acc[2][nt], 0, 0, 0);
            acc[3][nt] = __builtin_amdgcn_mfma_f32_16x16x32_bf16(af3, bf, acc[3][nt], 0, 0, 0);
        }
        __builtin_amdgcn_s_setprio(0);
        buf ^= 1;
        w1c0 = w1n0; w1c1 = w1n1; b1c0 = b1n0; b1c1 = b1n1;
    }

    // ---- fold this wave's panel into pm: pm[e,o] += x[e,i] * w[e,32i+o] ----
    {
        const int nblk = nblk0 + wc;
        #pragma unroll
        for (int ii = 0; ii < 4; ++ii) {
            const int i  = nblk * 4 + ii;
            const int iq = i >> 3, io = i & 7;
            #pragma unroll
            for (int mt = 0; mt < 4; ++mt)
                #pragma unroll
                for (int r = 0; r < 4; ++r) {
                    const int e = wm * 64 + mt * 16 + lq * 4 + r;
                    const float x = bf2f(sXb[iq * 1024 + e * 8 + io]);
                    pm[mt*2+0][r] = fmaf(x, acc[mt][ii*2+0][r], pm[mt*2+0][r]);
                    pm[mt*2+1][r] = fmaf(x, acc[mt][ii*2+1][r], pm[mt*2+1][r]);
                }
        }
    }
    #undef STAGE2

    // ---- cross-wc reduce in dead sB ----
    __syncthreads();
    float* sRed = (float*)sB;   // 128 x 36 fp32 = 18.4KB <= 32KB
    if (wc == 0) {
        #pragma unroll
        for (int mt = 0; mt < 4; ++mt)
            #pragma unroll
            for (int r = 0; r < 4; ++r) {
                const int e = wm * 64 + mt * 16 + lq * 4 + r;
                sRed[e * 36 + lr]      = pm[mt*2][r];
                sRed[e * 36 + 16 + lr] = pm[mt*2+1][r];
            }
    }
    __syncthreads();
    if (wc == 1) {
        #pragma unroll
        for (int mt = 0; mt < 4; ++mt)
            #pragma unroll
            for (int r = 0; r < 4; ++r) {
                const int e = wm * 64 + mt * 16 + lq * 4 + r;
                sRed[e * 36 + lr]      += pm[mt*2][r];
                sRed[e * 36 + 16 + lr] += pm[mt*2+1][r];
            }
    }
    __syncthreads();

    // ---- scatter: lanes = 4 edges (lq) x 16 consecutive cols (lr) so the TCC
    // merges each instruction's dwords into line ops (R6 lesson).
    #pragma unroll
    for (int mt = 0; mt < 2; ++mt)
        #pragma unroll
        for (int r = 0; r < 4; ++r) {
            const int e = w * 32 + mt * 16 + lq * 4 + r;
            const int d = sD[e];
            if (d >= 0) {
                atomicAdd(agg + (size_t)d * 32 + lr,      sRed[e * 36 + lr]);
                atomicAdd(agg + (size_t)d * 32 + 16 + lr, sRed[e * 36 + 16 + lr]);
            }
        }
}

// h[n,o] = relu(agg/max(deg,1) + bias), in place over agg
__global__ __launch_bounds__(256) void k_node(
    float* __restrict__ agg, const float* __restrict__ deg,
    const float* __restrict__ cbias)
{
    const int idx = blockIdx.x * 256 + threadIdx.x;
    if (idx >= NNODES * 32) return;
    const int n = idx >> 5, o = idx & 31;
    const float d = fmaxf(deg[n], 1.0f);
    agg[idx] = fmaxf(agg[idx] / d + cbias[o], 0.0f);
}

__global__ __launch_bounds__(256) void k_cls(
    const float* __restrict__ h, const float* __restrict__ ef,
    const int* __restrict__ src, const int* __restrict__ dst,
    const int* __restrict__ eidx,
    const float* __restrict__ Wc1, const float* __restrict__ bc1,
    const float* __restrict__ Wc2, const float* __restrict__ bc2,
    float* __restrict__ out)
{
    __shared__ float s_w1[96 * 32];
    __shared__ float s_w2[96];
    __shared__ float s_b1[32];
    __shared__ float s_in[8][96];

    const int t = threadIdx.x;
    #pragma unroll
    for (int q = 0; q < 3; ++q)
        *(float4*)&s_w1[t * 12 + q * 4] = *(const float4*)&Wc1[t * 12 + q * 4];
    if (t < 96) s_w2[t] = Wc2[t];
    if (t >= 96 && t < 128) s_b1[t - 96] = bc1[t - 96];

    const int ee = t >> 5, l = t & 31;
    const int e  = blockIdx.x * 8 + ee;
    const int ei = eidx[e];
    const int s = src[ei], d = dst[ei];
    s_in[ee][l]      = h[(size_t)s * 32 + l];
    s_in[ee][32 + l] = h[(size_t)d * 32 + l];
    s_in[ee][64 + l] = ef[(size_t)ei * 32 + l];
    __syncthreads();

    float acc = s_b1[l];
    #pragma unroll
    for (int c = 0; c < 96; ++c) acc = fmaf(s_in[ee][c], s_w1[c * 32 + l], acc);
    acc = fmaxf(acc, 0.f);

    float p0 = acc * s_w2[l * 3 + 0];
    float p1 = acc * s_w2[l * 3 + 1];
    float p2 = acc * s_w2[l * 3 + 2];
    #pragma unroll
    for (int m = 1; m <= 16; m <<= 1) {
        p0 += __shfl_xor(p0, m);
        p1 += __shfl_xor(p1, m);
        p2 += __shfl_xor(p2, m);
    }
    if (l == 0) {
        out[(size_t)e * 3 + 0] = p0 + bc2[0];
        out[(size_t)e * 3 + 1] = p1 + bc2[1];
        out[(size_t)e * 3 + 2] = p2 + bc2[2];
    }
}

extern "C" void kernel_launch(void* const* d_in, const int* in_sizes, int n_in,
                              void* d_out, int out_size, void* d_ws, size_t ws_size,
                              hipStream_t stream) {
    const float* nf   = (const float*)d_in[0];
    const float* ef   = (const float*)d_in[1];
    const int*   src  = (const int*)d_in[2];
    const int*   dst  = (const int*)d_in[3];
    const int*   eidx = (const int*)d_in[4];
    const float* W1   = (const float*)d_in[5];
    const float* b1   = (const float*)d_in[6];
    const float* W2   = (const float*)d_in[7];
    const float* b2   = (const float*)d_in[8];
    const float* cb   = (const float*)d_in[9];
    const float* Wc1  = (const float*)d_in[10];
    const float* bc1  = (const float*)d_in[11];
    const float* Wc2  = (const float*)d_in[12];
    const float* bc2  = (const float*)d_in[13];
    float* out = (float*)d_out;

    float* agg = (float*)d_ws;                               // 1,600,000 f32
    float* deg = agg + (size_t)NNODES * 32;                  // 50,000 f32
    unsigned short* w2p  = (unsigned short*)(deg + NNODES);  // 1,048,576 bf16
    unsigned short* w1pT = w2p + 1048576;                    // 32,768 bf16

    hipMemsetAsync(d_ws, 0, ((size_t)NNODES * 32 + NNODES) * 4, stream);
    k_pack<<<4096, 256, 0, stream>>>(W2, w2p);
    k_packw1<<<128, 256, 0, stream>>>(W1, w1pT);

    k_gemm<<<dim3((NEDGES + 127) / 128, 4), 256, 0, stream>>>(
        w2p, w1pT, ef, nf, b1, b2, src, dst, agg, deg);

    k_node<<<(NNODES * 32 + 255) / 256, 256, 0, stream>>>(agg, deg, cb);
    k_cls<<<NEDGES / 8, 256, 0, stream>>>(agg, ef, src, dst, eidx, Wc1, bc1, Wc2, bc2, out);
}